// Round 9
// baseline (992.556 us; speedup 1.0000x reference)
//
#include <hip/hip_runtime.h>
#include <hip/hip_bf16.h>
#include <stdint.h>

#define NN 100000
#define NE 1600000
#define BNEPS 1e-5f
#define NBKT 391            // ceil(NN/256)
#define NBA  256            // phase-A blocks
#define CHUNK ((NE + NBA - 1) / NBA)   // 6250

using short8 = __attribute__((ext_vector_type(8))) short;
using f32x4  = __attribute__((ext_vector_type(4))) float;

__device__ __forceinline__ float b2f(ushort u) {
  union { uint32_t u; float f; } c; c.u = ((uint32_t)u) << 16; return c.f;
}
__device__ __forceinline__ ushort f2bf(float f) {
  union { float f; uint32_t u; } c; c.f = f;
  uint32_t r = (c.u + 0x7FFFu + ((c.u >> 16) & 1u)) >> 16;
  return (ushort)r;
}
__device__ __forceinline__ uint pk(float a, float b) {
  return (uint)f2bf(a) | ((uint)f2bf(b) << 16);
}
__device__ __forceinline__ void gload16(const void* g, void* lds) {
  __builtin_amdgcn_global_load_lds((const __attribute__((address_space(1))) void*)g,
                                   (__attribute__((address_space(3))) void*)lds,
                                   16, 0, 0);
}
__device__ __forceinline__ void add16(float* a, uint4 q) {
  a[0] += b2f((ushort)(q.x & 0xFFFF)); a[1] += b2f((ushort)(q.x >> 16));
  a[2] += b2f((ushort)(q.y & 0xFFFF)); a[3] += b2f((ushort)(q.y >> 16));
  a[4] += b2f((ushort)(q.z & 0xFFFF)); a[5] += b2f((ushort)(q.z >> 16));
  a[6] += b2f((ushort)(q.w & 0xFFFF)); a[7] += b2f((ushort)(q.w >> 16));
}
__device__ __forceinline__ void set16(float* a, uint4 q) {
  a[0] = b2f((ushort)(q.x & 0xFFFF)); a[1] = b2f((ushort)(q.x >> 16));
  a[2] = b2f((ushort)(q.y & 0xFFFF)); a[3] = b2f((ushort)(q.y >> 16));
  a[4] = b2f((ushort)(q.z & 0xFFFF)); a[5] = b2f((ushort)(q.z >> 16));
  a[6] = b2f((ushort)(q.w & 0xFFFF)); a[7] = b2f((ushort)(q.w >> 16));
}

// ---------------- CSR build: LDS-histogram counting sort ----------------
__global__ __launch_bounds__(256) void k_hist(const int* __restrict__ dst, int* __restrict__ ghist) {
  __shared__ int h[NBKT];
  for (int t = threadIdx.x; t < NBKT; t += 256) h[t] = 0;
  __syncthreads();
  int e0 = blockIdx.x * CHUNK;
  int e1 = e0 + CHUNK; if (e1 > NE) e1 = NE;
  for (int e = e0 + threadIdx.x; e < e1; e += 256)
    atomicAdd(&h[((uint)dst[e]) >> 8], 1);
  __syncthreads();
  for (int t = threadIdx.x; t < NBKT; t += 256) ghist[t * NBA + blockIdx.x] = h[t];
}

__global__ __launch_bounds__(256) void k_gscanA(const int* __restrict__ ghist, int* __restrict__ gbase,
                                                int* __restrict__ btot) {
  __shared__ int s[256];
  int t = threadIdx.x, b = blockIdx.x;
  int d = ghist[b * NBA + t];
  s[t] = d; __syncthreads();
  int val = d;
  for (int sh = 1; sh < 256; sh <<= 1) {
    int tv = (t >= sh) ? s[t - sh] : 0;
    __syncthreads();
    val += tv; s[t] = val;
    __syncthreads();
  }
  gbase[b * NBA + t] = val - d;
  if (t == 255) btot[b] = val;
}

__global__ __launch_bounds__(512) void k_bscan(const int* __restrict__ btot, int* __restrict__ bbase,
                                               int* __restrict__ offs) {
  __shared__ int s[512];
  int t = threadIdx.x;
  int d = (t < NBKT) ? btot[t] : 0;
  s[t] = d; __syncthreads();
  int val = d;
  for (int sh = 1; sh < 512; sh <<= 1) {
    int tv = (t >= sh) ? s[t - sh] : 0;
    __syncthreads();
    val += tv; s[t] = val;
    __syncthreads();
  }
  if (t < NBKT) bbase[t] = val - d;
  if (t == 0) offs[NN] = NE;
}

__global__ __launch_bounds__(256) void k_scatter(const int* __restrict__ src, const int* __restrict__ dst,
                                                 const int* __restrict__ bbase, const int* __restrict__ gbase,
                                                 uint* __restrict__ bpack) {
  __shared__ int lbase[NBKT];
  for (int t = threadIdx.x; t < NBKT; t += 256)
    lbase[t] = bbase[t] + gbase[t * NBA + blockIdx.x];
  __syncthreads();
  int e0 = blockIdx.x * CHUNK;
  int e1 = e0 + CHUNK; if (e1 > NE) e1 = NE;
  for (int e = e0 + threadIdx.x; e < e1; e += 256) {
    int d = dst[e];
    int pos = atomicAdd(&lbase[((uint)d) >> 8], 1);
    bpack[pos] = ((uint)(d & 255) << 17) | (uint)src[e];
  }
}

__global__ __launch_bounds__(256) void k_bucketB(const uint* __restrict__ bpack, const int* __restrict__ btot,
                                                 const int* __restrict__ bbase, int* __restrict__ csrc,
                                                 int* __restrict__ offs, float* __restrict__ dinv) {
  __shared__ int hist[256];
  __shared__ int sc[256];
  __shared__ int loc[256];
  int b = blockIdx.x, t = threadIdx.x;
  int cnt = btot[b], base = bbase[b];
  const uint* bp = bpack + base;
  hist[t] = 0; __syncthreads();
  for (int i = t; i < cnt; i += 256) atomicAdd(&hist[bp[i] >> 17], 1);
  __syncthreads();
  int d = hist[t];
  sc[t] = d; __syncthreads();
  int val = d;
  for (int sh = 1; sh < 256; sh <<= 1) {
    int tv = (t >= sh) ? sc[t - sh] : 0;
    __syncthreads();
    val += tv; sc[t] = val;
    __syncthreads();
  }
  loc[t] = val - d;
  int n = b * 256 + t;
  if (n < NN) {
    offs[n] = base + val - d;
    dinv[n] = rsqrtf((float)d + 1.0f);
  }
  __syncthreads();
  for (int i = t; i < cnt; i += 256) {
    uint p = bp[i];
    int l = p >> 17, s = p & 0x1FFFF;
    int pos = atomicAdd(&loc[l], 1);
    csrc[base + pos] = s;
  }
}

// ---------------- weight prep ----------------
__global__ __launch_bounds__(256) void k_prep(
    const float* __restrict__ W0, const float* __restrict__ W1, const float* __restrict__ W2,
    const float* __restrict__ W3, const float* __restrict__ b0, const float* __restrict__ b1,
    const float* __restrict__ b2, const float* __restrict__ gamma, const float* __restrict__ beta,
    const float* __restrict__ rm, const float* __restrict__ rv,
    ushort* __restrict__ W0t, ushort* __restrict__ W1t, ushort* __restrict__ W2t,
    ushort* __restrict__ W3t, float* __restrict__ bnA, float* __restrict__ bnB) {
  int tid = blockIdx.x * blockDim.x + threadIdx.x;
  int nthr = gridDim.x * blockDim.x;
  for (int i = tid; i < 256 * 128; i += nthr) { int m = i >> 7, k = i & 127; W0t[i] = f2bf(W0[k * 256 + m]); }
  for (int i = tid; i < 256 * 256; i += nthr) {
    int m = i >> 8, k = i & 255;
    W1t[i] = f2bf(W1[k * 256 + m]);
    W2t[i] = f2bf(W2[k * 256 + m]);
  }
  for (int i = tid; i < 32 * 256; i += nthr) {
    int m = i >> 8, k = i & 255;
    W3t[i] = (m < 20) ? f2bf(W3[k * 20 + m]) : (ushort)0;
  }
  for (int i = tid; i < 3 * 256; i += nthr) {
    int l = i >> 8, c = i & 255;
    float A = gamma[i] * rsqrtf(rv[i] + BNEPS);
    float bb = (l == 0) ? b0[c] : (l == 1) ? b1[c] : b2[c];
    bnA[i] = A;
    bnB[i] = (bb - rm[i]) * A + beta[i];
  }
}

// ---------------- x -> bf16, pre-scaled by dinv[row] ----------------
__global__ __launch_bounds__(256) void k_convx(const float4* __restrict__ x, uint2* __restrict__ xb,
                                               const float* __restrict__ dinv) {
  int stride = gridDim.x * blockDim.x;
  const int n4 = NN * 128 / 4;
  for (int i = blockIdx.x * blockDim.x + threadIdx.x; i < n4; i += stride) {
    float4 f = x[i];
    float dv = dinv[i >> 5];
    uint2 o;
    o.x = pk(f.x * dv, f.y * dv);
    o.y = pk(f.z * dv, f.w * dv);
    xb[i] = o;
  }
}

// ---------------- gather aggregation ----------------
// Z rows PRE-SCALED by dinv[u]:  out[v] = (zs[v] + sum_u zs[u]) * dinv[v]

// Feature-sliced 256-wide agg: slice = blockIdx.x & 7 (round-robins onto XCDs ->
// per-XCD working set = 6.4 MB slice of the table). 32 feats (64B) per edge,
// 16 lanes x 4B, 4 edge-slots per wave.
__global__ __launch_bounds__(256) void k_agg256s(const ushort* __restrict__ Z,
                                                 const int* __restrict__ offs, const int* __restrict__ csrc,
                                                 const float* __restrict__ dinv, ushort* __restrict__ Outb) {
  int wave = threadIdx.x >> 6, lane = threadIdx.x & 63;
  int s = blockIdx.x & 7;
  int v = (blockIdx.x >> 3) * 4 + wave;
  if (v >= NN) return;
  float dv = dinv[v];
  int slot = lane >> 4, fl = lane & 15;
  const uint* Zu = reinterpret_cast<const uint*>(Z);   // 128 uint per row
  int base = s * 16 + fl;
  float a0, a1;
  if (slot == 0) {
    uint q = Zu[(size_t)v * 128 + base];
    a0 = b2f((ushort)(q & 0xFFFF));
    a1 = b2f((ushort)(q >> 16));
  } else {
    a0 = 0.0f; a1 = 0.0f;
  }
  int e1 = offs[v + 1];
  int e = offs[v] + slot;
  for (; e + 12 < e1; e += 16) {
    int u0 = csrc[e], u1 = csrc[e + 4], u2 = csrc[e + 8], u3 = csrc[e + 12];
    uint q0 = Zu[(size_t)u0 * 128 + base];
    uint q1 = Zu[(size_t)u1 * 128 + base];
    uint q2 = Zu[(size_t)u2 * 128 + base];
    uint q3 = Zu[(size_t)u3 * 128 + base];
    a0 += (b2f((ushort)(q0 & 0xFFFF)) + b2f((ushort)(q1 & 0xFFFF)))
        + (b2f((ushort)(q2 & 0xFFFF)) + b2f((ushort)(q3 & 0xFFFF)));
    a1 += (b2f((ushort)(q0 >> 16)) + b2f((ushort)(q1 >> 16)))
        + (b2f((ushort)(q2 >> 16)) + b2f((ushort)(q3 >> 16)));
  }
  for (; e < e1; e += 4) {
    uint q = Zu[(size_t)csrc[e] * 128 + base];
    a0 += b2f((ushort)(q & 0xFFFF));
    a1 += b2f((ushort)(q >> 16));
  }
  a0 += __shfl_xor(a0, 16); a0 += __shfl_xor(a0, 32);
  a1 += __shfl_xor(a1, 16); a1 += __shfl_xor(a1, 32);
  if (slot == 0)
    reinterpret_cast<uint*>(Outb)[(size_t)v * 128 + base] = pk(a0 * dv, a1 * dv);
}

__global__ __launch_bounds__(256) void k_agg128(const ushort* __restrict__ Z,
                                                const int* __restrict__ offs, const int* __restrict__ csrc,
                                                const float* __restrict__ dinv, ushort* __restrict__ Outb) {
  int wave = threadIdx.x >> 6, lane = threadIdx.x & 63;
  int v = blockIdx.x * 4 + wave;
  if (v >= NN) return;
  float dv = dinv[v];
  int q = lane >> 4, fl = lane & 15;
  const uint4* Z4 = reinterpret_cast<const uint4*>(Z);   // 16 uint4 per row
  float acc[8];
  if (q == 0) {
    set16(acc, Z4[(size_t)v * 16 + fl]);
  } else {
#pragma unroll
    for (int j = 0; j < 8; ++j) acc[j] = 0.0f;
  }
  int e1 = offs[v + 1];
  int e = offs[v] + q;
  for (; e + 12 < e1; e += 16) {
    int u0 = csrc[e], u1 = csrc[e + 4], u2 = csrc[e + 8], u3 = csrc[e + 12];
    uint4 q0 = Z4[(size_t)u0 * 16 + fl];
    uint4 q1 = Z4[(size_t)u1 * 16 + fl];
    uint4 q2 = Z4[(size_t)u2 * 16 + fl];
    uint4 q3 = Z4[(size_t)u3 * 16 + fl];
    add16(acc, q0); add16(acc, q1); add16(acc, q2); add16(acc, q3);
  }
  for (; e < e1; e += 4) add16(acc, Z4[(size_t)csrc[e] * 16 + fl]);
#pragma unroll
  for (int j = 0; j < 8; ++j) {
    acc[j] += __shfl_xor(acc[j], 16);
    acc[j] += __shfl_xor(acc[j], 32);
  }
  uint w = pk(acc[2 * q] * dv, acc[2 * q + 1] * dv);
  reinterpret_cast<uint*>(Outb)[(size_t)v * 64 + fl * 4 + q] = w;
}

__global__ __launch_bounds__(256) void k_aggfin(const ushort* __restrict__ Z,
                                                const int* __restrict__ offs, const int* __restrict__ csrc,
                                                const float* __restrict__ dinv, const float* __restrict__ b3,
                                                float* __restrict__ out) {
  int wave = threadIdx.x >> 6, lane = threadIdx.x & 63;
  int v = blockIdx.x * 4 + wave;
  if (v >= NN) return;
  float dv = dinv[v];
  int s = lane >> 3, fl = lane & 7;
  const uint2* Z2 = reinterpret_cast<const uint2*>(Z);   // 8 uint2 per row
  float acc[4];
  if (s == 0) {
    uint2 qq = Z2[(size_t)v * 8 + fl];
    acc[0] = b2f((ushort)(qq.x & 0xFFFF)); acc[1] = b2f((ushort)(qq.x >> 16));
    acc[2] = b2f((ushort)(qq.y & 0xFFFF)); acc[3] = b2f((ushort)(qq.y >> 16));
  } else {
    acc[0] = acc[1] = acc[2] = acc[3] = 0.0f;
  }
  int e1 = offs[v + 1];
  int e = offs[v] + s;
  for (; e + 8 < e1; e += 16) {
    int u0 = csrc[e], u1 = csrc[e + 8];
    uint2 q0 = Z2[(size_t)u0 * 8 + fl];
    uint2 q1 = Z2[(size_t)u1 * 8 + fl];
    acc[0] += b2f((ushort)(q0.x & 0xFFFF)) + b2f((ushort)(q1.x & 0xFFFF));
    acc[1] += b2f((ushort)(q0.x >> 16))    + b2f((ushort)(q1.x >> 16));
    acc[2] += b2f((ushort)(q0.y & 0xFFFF)) + b2f((ushort)(q1.y & 0xFFFF));
    acc[3] += b2f((ushort)(q0.y >> 16))    + b2f((ushort)(q1.y >> 16));
  }
  for (; e < e1; e += 8) {
    uint2 qq = Z2[(size_t)csrc[e] * 8 + fl];
    acc[0] += b2f((ushort)(qq.x & 0xFFFF)); acc[1] += b2f((ushort)(qq.x >> 16));
    acc[2] += b2f((ushort)(qq.y & 0xFFFF)); acc[3] += b2f((ushort)(qq.y >> 16));
  }
#pragma unroll
  for (int j = 0; j < 4; ++j) {
    acc[j] += __shfl_xor(acc[j], 8);
    acc[j] += __shfl_xor(acc[j], 16);
    acc[j] += __shfl_xor(acc[j], 32);
  }
  if (s == 0 && fl < 5) {
    float4 w;
    w.x = acc[0] * dv + b3[fl * 4 + 0];
    w.y = acc[1] * dv + b3[fl * 4 + 1];
    w.z = acc[2] * dv + b3[fl * 4 + 2];
    w.w = acc[3] * dv + b3[fl * 4 + 3];
    *reinterpret_cast<float4*>(out + (size_t)v * 20 + fl * 4) = w;
  }
}

// ---------------- MFMA GEMM (R6 configuration) ----------------
template<int KTOT, int BN, bool EPI, bool SCALE>
__global__ __launch_bounds__(256) void k_gemm(const ushort* __restrict__ A,
                                              const ushort* __restrict__ Bt,   // [cols][KTOT]
                                              ushort* __restrict__ Out,
                                              const float* __restrict__ bnA,
                                              const float* __restrict__ bnB,
                                              const float* __restrict__ dinv, int outW) {
  constexpr int BM = 128, BK = 64;
  constexpr int WN = (BN == 128) ? 64 : 16;
  constexpr int WM = 64;
  constexpr int FM = WM / 16, FN = WN / 16;
  __shared__ ushort Alds[BM * BK];
  __shared__ ushort Blds[BN * BK];
  int tid = threadIdx.x;
  int lane = tid & 63;
  int wave = tid >> 6;
  int wm = wave >> 1, wn = wave & 1;
  size_t row0 = (size_t)blockIdx.x * BM;
  int col0 = blockIdx.y * BN;

  f32x4 acc[FM][FN];
#pragma unroll
  for (int i = 0; i < FM; ++i)
#pragma unroll
    for (int j = 0; j < FN; ++j)
#pragma unroll
      for (int r = 0; r < 4; ++r) acc[i][j][r] = 0.0f;

  for (int k0 = 0; k0 < KTOT; k0 += BK) {
#pragma unroll
    for (int is = 0; is < 4; ++is) {
      int idx = is * 256 + tid;
      int r = idx >> 3, c = idx & 7;
      size_t gr = row0 + r; if (gr >= NN) gr = NN - 1;
      gload16(A + gr * KTOT + k0 + c * 8, &Alds[(size_t)(idx & ~63) * 8]);
    }
#pragma unroll
    for (int is = 0; is < BN / 32; ++is) {
      int idx = is * 256 + tid;
      int r = idx >> 3, c = idx & 7;
      gload16(Bt + (size_t)(col0 + r) * KTOT + k0 + c * 8, &Blds[(size_t)(idx & ~63) * 8]);
    }
    __syncthreads();
#pragma unroll
    for (int kk = 0; kk < BK; kk += 32) {
      short8 af[FM]; short8 bfr[FN];
#pragma unroll
      for (int fm = 0; fm < FM; ++fm)
        af[fm] = *reinterpret_cast<const short8*>(&Alds[(wm * WM + fm * 16 + (lane & 15)) * BK + kk + (lane >> 4) * 8]);
#pragma unroll
      for (int fn = 0; fn < FN; ++fn)
        bfr[fn] = *reinterpret_cast<const short8*>(&Blds[(wn * WN + fn * 16 + (lane & 15)) * BK + kk + (lane >> 4) * 8]);
#pragma unroll
      for (int fm = 0; fm < FM; ++fm)
#pragma unroll
        for (int fn = 0; fn < FN; ++fn)
          acc[fm][fn] = __builtin_amdgcn_mfma_f32_16x16x32_bf16(af[fm], bfr[fn], acc[fm][fn], 0, 0, 0);
    }
    __syncthreads();
  }

  int lr = (lane >> 4) * 4, lc = lane & 15;
#pragma unroll
  for (int fm = 0; fm < FM; ++fm) {
#pragma unroll
    for (int r = 0; r < 4; ++r) {
      size_t grow = row0 + wm * WM + fm * 16 + lr + r;
      if (grow >= NN) continue;
      float ds = 1.0f;
      if constexpr (SCALE) ds = dinv[grow];
#pragma unroll
      for (int fn = 0; fn < FN; ++fn) {
        int gcol = col0 + wn * WN + fn * 16 + lc;
        float v = acc[fm][fn][r];
        if constexpr (EPI) v = fmaxf(v * bnA[gcol] + bnB[gcol], 0.0f);
        if constexpr (SCALE) v *= ds;
        Out[grow * outW + gcol] = f2bf(v);
      }
    }
  }
}

extern "C" void kernel_launch(void* const* d_in, const int* in_sizes, int n_in,
                              void* d_out, int out_size, void* d_ws, size_t ws_size,
                              hipStream_t stream) {
  (void)in_sizes; (void)n_in; (void)out_size; (void)ws_size;
  const float* x     = (const float*)d_in[0];
  const int*   ei    = (const int*)d_in[1];
  const float* W0    = (const float*)d_in[2];
  const float* b0    = (const float*)d_in[3];
  const float* W1    = (const float*)d_in[4];
  const float* b1    = (const float*)d_in[5];
  const float* W2    = (const float*)d_in[6];
  const float* b2    = (const float*)d_in[7];
  const float* W3    = (const float*)d_in[8];
  const float* b3    = (const float*)d_in[9];
  const float* gamma = (const float*)d_in[10];
  const float* beta  = (const float*)d_in[11];
  const float* rm    = (const float*)d_in[12];
  const float* rv    = (const float*)d_in[13];
  const int* src = ei;
  const int* dst = ei + NE;
  float* out = (float*)d_out;

  char* ws = (char*)d_ws;
  size_t off = 0;
  auto alloc = [&](size_t bytes) -> void* {
    void* p = ws + off; off += (bytes + 255) & ~(size_t)255; return p;
  };
  int*    ghist = (int*)alloc((size_t)NBKT * NBA * 4);
  int*    gbase = (int*)alloc((size_t)NBKT * NBA * 4);
  int*    btot  = (int*)alloc(NBKT * 4);
  int*    bbase = (int*)alloc(NBKT * 4);
  uint*   bpack = (uint*)alloc((size_t)NE * 4);
  int*    offs  = (int*)alloc((NN + 1) * (size_t)4);
  int*    csrc  = (int*)alloc((size_t)NE * 4);
  float*  dinv  = (float*)alloc(NN * 4);
  ushort* W0t   = (ushort*)alloc(256 * 128 * 2);
  ushort* W1t   = (ushort*)alloc(256 * 256 * 2);
  ushort* W2t   = (ushort*)alloc(256 * 256 * 2);
  ushort* W3t   = (ushort*)alloc(32 * 256 * 2);
  float*  bnA   = (float*)alloc(3 * 256 * 4);
  float*  bnB   = (float*)alloc(3 * 256 * 4);
  ushort* bufS  = (ushort*)alloc((size_t)NN * 128 * 2);   // x_bf16*dinv / z3*dinv
  ushort* bufA  = (ushort*)alloc((size_t)NN * 256 * 2);   // agg outputs
  ushort* bufB  = (ushort*)alloc((size_t)NN * 256 * 2);   // gemm outputs

  k_hist<<<NBA, 256, 0, stream>>>(dst, ghist);
  k_gscanA<<<NBKT, 256, 0, stream>>>(ghist, gbase, btot);
  k_bscan<<<1, 512, 0, stream>>>(btot, bbase, offs);
  k_scatter<<<NBA, 256, 0, stream>>>(src, dst, bbase, gbase, bpack);
  k_bucketB<<<NBKT, 256, 0, stream>>>(bpack, btot, bbase, csrc, offs, dinv);
  k_prep<<<256, 256, 0, stream>>>(W0, W1, W2, W3, b0, b1, b2, gamma, beta, rm, rv,
                                  W0t, W1t, W2t, W3t, bnA, bnB);
  k_convx<<<2048, 256, 0, stream>>>((const float4*)x, (uint2*)bufS, dinv);

  const int aggBlocks = (NN + 3) / 4;       // 25000
  const int aggSBlocks = aggBlocks * 8;     // sliced: 8 slice-blocks per node-group
  dim3 gMain((NN + 127) / 128, 2);
  dim3 gLast((NN + 127) / 128, 1);

  // L0: aggregate(x*dinv)[128] -> GEMM 128->256 (+BN+ReLU, out *= dinv)
  k_agg128<<<aggBlocks, 256, 0, stream>>>(bufS, offs, csrc, dinv, bufA);
  k_gemm<128, 128, true, true><<<gMain, 256, 0, stream>>>(bufA, W0t, bufB, bnA, bnB, dinv, 256);
  // L1 (out *= dinv, feeds agg2)
  k_agg256s<<<aggSBlocks, 256, 0, stream>>>(bufB, offs, csrc, dinv, bufA);
  k_gemm<256, 128, true, true><<<gMain, 256, 0, stream>>>(bufA, W1t, bufB, bnA + 256, bnB + 256, dinv, 256);
  // L2 (NO dinv scale — output feeds GEMM3 directly)
  k_agg256s<<<aggSBlocks, 256, 0, stream>>>(bufB, offs, csrc, dinv, bufA);
  k_gemm<256, 128, true, false><<<gMain, 256, 0, stream>>>(bufA, W2t, bufB, bnA + 512, bnB + 512, nullptr, 256);
  // L3: GEMM 256->20 (padded 32, out *= dinv), then aggregate + b3 -> fp32 out
  k_gemm<256, 32, false, true><<<gLast, 256, 0, stream>>>(bufB, W3t, bufS, nullptr, nullptr, dinv, 32);
  k_aggfin<<<aggBlocks, 256, 0, stream>>>(bufS, offs, csrc, dinv, b3, out);
}

// Round 10
// 551.642 us; speedup vs baseline: 1.7993x; 1.7993x over previous
//
#include <hip/hip_runtime.h>
#include <hip/hip_bf16.h>
#include <stdint.h>

#define NN 100000
#define NE 1600000
#define BNEPS 1e-5f
#define NBKT 391            // ceil(NN/256)
#define NBA  512            // phase-A blocks
#define CHUNK ((NE + NBA - 1) / NBA)   // 3125

using short8 = __attribute__((ext_vector_type(8))) short;
using f32x4  = __attribute__((ext_vector_type(4))) float;

__device__ __forceinline__ float b2f(ushort u) {
  union { uint32_t u; float f; } c; c.u = ((uint32_t)u) << 16; return c.f;
}
__device__ __forceinline__ ushort f2bf(float f) {
  union { float f; uint32_t u; } c; c.f = f;
  uint32_t r = (c.u + 0x7FFFu + ((c.u >> 16) & 1u)) >> 16;
  return (ushort)r;
}
__device__ __forceinline__ uint pk(float a, float b) {
  return (uint)f2bf(a) | ((uint)f2bf(b) << 16);
}
__device__ __forceinline__ void gload16(const void* g, void* lds) {
  __builtin_amdgcn_global_load_lds((const __attribute__((address_space(1))) void*)g,
                                   (__attribute__((address_space(3))) void*)lds,
                                   16, 0, 0);
}
__device__ __forceinline__ void add16(float* a, uint4 q) {
  a[0] += b2f((ushort)(q.x & 0xFFFF)); a[1] += b2f((ushort)(q.x >> 16));
  a[2] += b2f((ushort)(q.y & 0xFFFF)); a[3] += b2f((ushort)(q.y >> 16));
  a[4] += b2f((ushort)(q.z & 0xFFFF)); a[5] += b2f((ushort)(q.z >> 16));
  a[6] += b2f((ushort)(q.w & 0xFFFF)); a[7] += b2f((ushort)(q.w >> 16));
}
__device__ __forceinline__ void set16(float* a, uint4 q) {
  a[0] = b2f((ushort)(q.x & 0xFFFF)); a[1] = b2f((ushort)(q.x >> 16));
  a[2] = b2f((ushort)(q.y & 0xFFFF)); a[3] = b2f((ushort)(q.y >> 16));
  a[4] = b2f((ushort)(q.z & 0xFFFF)); a[5] = b2f((ushort)(q.z >> 16));
  a[6] = b2f((ushort)(q.w & 0xFFFF)); a[7] = b2f((ushort)(q.w >> 16));
}

// ---------------- CSR build: LDS-histogram counting sort ----------------
__global__ __launch_bounds__(256) void k_hist(const int* __restrict__ dst, int* __restrict__ ghist) {
  __shared__ int h[NBKT];
  for (int t = threadIdx.x; t < NBKT; t += 256) h[t] = 0;
  __syncthreads();
  int e0 = blockIdx.x * CHUNK;
  int e1 = e0 + CHUNK; if (e1 > NE) e1 = NE;
  for (int e = e0 + threadIdx.x; e < e1; e += 256)
    atomicAdd(&h[((uint)dst[e]) >> 8], 1);
  __syncthreads();
  for (int t = threadIdx.x; t < NBKT; t += 256) ghist[t * NBA + blockIdx.x] = h[t];
}

__global__ __launch_bounds__(512) void k_gscanA(const int* __restrict__ ghist, int* __restrict__ gbase,
                                                int* __restrict__ btot) {
  __shared__ int s[NBA];
  int t = threadIdx.x, b = blockIdx.x;
  int d = ghist[b * NBA + t];
  s[t] = d; __syncthreads();
  int val = d;
  for (int sh = 1; sh < NBA; sh <<= 1) {
    int tv = (t >= sh) ? s[t - sh] : 0;
    __syncthreads();
    val += tv; s[t] = val;
    __syncthreads();
  }
  gbase[b * NBA + t] = val - d;
  if (t == NBA - 1) btot[b] = val;
}

__global__ __launch_bounds__(512) void k_bscan(const int* __restrict__ btot, int* __restrict__ bbase,
                                               int* __restrict__ offs) {
  __shared__ int s[512];
  int t = threadIdx.x;
  int d = (t < NBKT) ? btot[t] : 0;
  s[t] = d; __syncthreads();
  int val = d;
  for (int sh = 1; sh < 512; sh <<= 1) {
    int tv = (t >= sh) ? s[t - sh] : 0;
    __syncthreads();
    val += tv; s[t] = val;
    __syncthreads();
  }
  if (t < NBKT) bbase[t] = val - d;
  if (t == 0) offs[NN] = NE;
}

__global__ __launch_bounds__(256) void k_scatter(const int* __restrict__ src, const int* __restrict__ dst,
                                                 const int* __restrict__ bbase, const int* __restrict__ gbase,
                                                 uint* __restrict__ bpack) {
  __shared__ int lbase[NBKT];
  for (int t = threadIdx.x; t < NBKT; t += 256)
    lbase[t] = bbase[t] + gbase[t * NBA + blockIdx.x];
  __syncthreads();
  int e0 = blockIdx.x * CHUNK;
  int e1 = e0 + CHUNK; if (e1 > NE) e1 = NE;
  for (int e = e0 + threadIdx.x; e < e1; e += 256) {
    int d = dst[e];
    int pos = atomicAdd(&lbase[((uint)d) >> 8], 1);
    bpack[pos] = ((uint)(d & 255) << 17) | (uint)src[e];
  }
}

__global__ __launch_bounds__(256) void k_bucketB(const uint* __restrict__ bpack, const int* __restrict__ btot,
                                                 const int* __restrict__ bbase, int* __restrict__ csrc,
                                                 int* __restrict__ offs, float* __restrict__ dinv) {
  __shared__ int hist[256];
  __shared__ int sc[256];
  __shared__ int loc[256];
  int b = blockIdx.x, t = threadIdx.x;
  int cnt = btot[b], base = bbase[b];
  const uint* bp = bpack + base;
  hist[t] = 0; __syncthreads();
  for (int i = t; i < cnt; i += 256) atomicAdd(&hist[bp[i] >> 17], 1);
  __syncthreads();
  int d = hist[t];
  sc[t] = d; __syncthreads();
  int val = d;
  for (int sh = 1; sh < 256; sh <<= 1) {
    int tv = (t >= sh) ? sc[t - sh] : 0;
    __syncthreads();
    val += tv; sc[t] = val;
    __syncthreads();
  }
  loc[t] = val - d;
  int n = b * 256 + t;
  if (n < NN) {
    offs[n] = base + val - d;
    dinv[n] = rsqrtf((float)d + 1.0f);
  }
  __syncthreads();
  for (int i = t; i < cnt; i += 256) {
    uint p = bp[i];
    int l = p >> 17, s = p & 0x1FFFF;
    int pos = atomicAdd(&loc[l], 1);
    csrc[base + pos] = s;
  }
}

// ---------------- weight prep ----------------
__global__ __launch_bounds__(256) void k_prep(
    const float* __restrict__ W0, const float* __restrict__ W1, const float* __restrict__ W2,
    const float* __restrict__ W3, const float* __restrict__ b0, const float* __restrict__ b1,
    const float* __restrict__ b2, const float* __restrict__ gamma, const float* __restrict__ beta,
    const float* __restrict__ rm, const float* __restrict__ rv,
    ushort* __restrict__ W0t, ushort* __restrict__ W1t, ushort* __restrict__ W2t,
    ushort* __restrict__ W3t, float* __restrict__ bnA, float* __restrict__ bnB) {
  int tid = blockIdx.x * blockDim.x + threadIdx.x;
  int nthr = gridDim.x * blockDim.x;
  for (int i = tid; i < 256 * 128; i += nthr) { int m = i >> 7, k = i & 127; W0t[i] = f2bf(W0[k * 256 + m]); }
  for (int i = tid; i < 256 * 256; i += nthr) {
    int m = i >> 8, k = i & 255;
    W1t[i] = f2bf(W1[k * 256 + m]);
    W2t[i] = f2bf(W2[k * 256 + m]);
  }
  for (int i = tid; i < 32 * 256; i += nthr) {
    int m = i >> 8, k = i & 255;
    W3t[i] = (m < 20) ? f2bf(W3[k * 20 + m]) : (ushort)0;
  }
  for (int i = tid; i < 3 * 256; i += nthr) {
    int l = i >> 8, c = i & 255;
    float A = gamma[i] * rsqrtf(rv[i] + BNEPS);
    float bb = (l == 0) ? b0[c] : (l == 1) ? b1[c] : b2[c];
    bnA[i] = A;
    bnB[i] = (bb - rm[i]) * A + beta[i];
  }
}

// ---------------- x -> bf16, pre-scaled by dinv[row] ----------------
__global__ __launch_bounds__(256) void k_convx(const float4* __restrict__ x, uint2* __restrict__ xb,
                                               const float* __restrict__ dinv) {
  int stride = gridDim.x * blockDim.x;
  const int n4 = NN * 128 / 4;
  for (int i = blockIdx.x * blockDim.x + threadIdx.x; i < n4; i += stride) {
    float4 f = x[i];
    float dv = dinv[i >> 5];
    uint2 o;
    o.x = pk(f.x * dv, f.y * dv);
    o.y = pk(f.z * dv, f.w * dv);
    xb[i] = o;
  }
}

// ---------------- gather aggregation (R6 config — structural floor) ----------------
// Z rows PRE-SCALED by dinv[u]:  out[v] = (zs[v] + sum_u zs[u]) * dinv[v]

__global__ __launch_bounds__(256) void k_agg256(const ushort* __restrict__ Z,
                                                const int* __restrict__ offs, const int* __restrict__ csrc,
                                                const float* __restrict__ dinv, ushort* __restrict__ Outb) {
  int wave = threadIdx.x >> 6, lane = threadIdx.x & 63;
  int v = blockIdx.x * 4 + wave;
  if (v >= NN) return;
  float dv = dinv[v];
  int p = lane >> 5, fl = lane & 31;
  const uint4* Z4 = reinterpret_cast<const uint4*>(Z);   // 32 uint4 per row
  float acc[8];
  if (p == 0) {
    set16(acc, Z4[(size_t)v * 32 + fl]);
  } else {
#pragma unroll
    for (int j = 0; j < 8; ++j) acc[j] = 0.0f;
  }
  int e1 = offs[v + 1];
  int e = offs[v] + p;
  for (; e + 6 < e1; e += 8) {
    int u0 = csrc[e], u1 = csrc[e + 2], u2 = csrc[e + 4], u3 = csrc[e + 6];
    uint4 q0 = Z4[(size_t)u0 * 32 + fl];
    uint4 q1 = Z4[(size_t)u1 * 32 + fl];
    uint4 q2 = Z4[(size_t)u2 * 32 + fl];
    uint4 q3 = Z4[(size_t)u3 * 32 + fl];
    add16(acc, q0); add16(acc, q1); add16(acc, q2); add16(acc, q3);
  }
  for (; e < e1; e += 2) add16(acc, Z4[(size_t)csrc[e] * 32 + fl]);
#pragma unroll
  for (int j = 0; j < 8; ++j) acc[j] += __shfl_xor(acc[j], 32);
  int o = p * 4;
  uint2 w;
  w.x = pk(acc[o + 0] * dv, acc[o + 1] * dv);
  w.y = pk(acc[o + 2] * dv, acc[o + 3] * dv);
  reinterpret_cast<uint2*>(Outb)[(size_t)v * 64 + fl * 2 + p] = w;
}

__global__ __launch_bounds__(256) void k_agg128(const ushort* __restrict__ Z,
                                                const int* __restrict__ offs, const int* __restrict__ csrc,
                                                const float* __restrict__ dinv, ushort* __restrict__ Outb) {
  int wave = threadIdx.x >> 6, lane = threadIdx.x & 63;
  int v = blockIdx.x * 4 + wave;
  if (v >= NN) return;
  float dv = dinv[v];
  int q = lane >> 4, fl = lane & 15;
  const uint4* Z4 = reinterpret_cast<const uint4*>(Z);   // 16 uint4 per row
  float acc[8];
  if (q == 0) {
    set16(acc, Z4[(size_t)v * 16 + fl]);
  } else {
#pragma unroll
    for (int j = 0; j < 8; ++j) acc[j] = 0.0f;
  }
  int e1 = offs[v + 1];
  int e = offs[v] + q;
  for (; e + 12 < e1; e += 16) {
    int u0 = csrc[e], u1 = csrc[e + 4], u2 = csrc[e + 8], u3 = csrc[e + 12];
    uint4 q0 = Z4[(size_t)u0 * 16 + fl];
    uint4 q1 = Z4[(size_t)u1 * 16 + fl];
    uint4 q2 = Z4[(size_t)u2 * 16 + fl];
    uint4 q3 = Z4[(size_t)u3 * 16 + fl];
    add16(acc, q0); add16(acc, q1); add16(acc, q2); add16(acc, q3);
  }
  for (; e < e1; e += 4) add16(acc, Z4[(size_t)csrc[e] * 16 + fl]);
#pragma unroll
  for (int j = 0; j < 8; ++j) {
    acc[j] += __shfl_xor(acc[j], 16);
    acc[j] += __shfl_xor(acc[j], 32);
  }
  uint w = pk(acc[2 * q] * dv, acc[2 * q + 1] * dv);
  reinterpret_cast<uint*>(Outb)[(size_t)v * 64 + fl * 4 + q] = w;
}

__global__ __launch_bounds__(256) void k_aggfin(const ushort* __restrict__ Z,
                                                const int* __restrict__ offs, const int* __restrict__ csrc,
                                                const float* __restrict__ dinv, const float* __restrict__ b3,
                                                float* __restrict__ out) {
  int wave = threadIdx.x >> 6, lane = threadIdx.x & 63;
  int v = blockIdx.x * 4 + wave;
  if (v >= NN) return;
  float dv = dinv[v];
  int s = lane >> 3, fl = lane & 7;
  const uint2* Z2 = reinterpret_cast<const uint2*>(Z);   // 8 uint2 per row
  float acc[4];
  if (s == 0) {
    uint2 qq = Z2[(size_t)v * 8 + fl];
    acc[0] = b2f((ushort)(qq.x & 0xFFFF)); acc[1] = b2f((ushort)(qq.x >> 16));
    acc[2] = b2f((ushort)(qq.y & 0xFFFF)); acc[3] = b2f((ushort)(qq.y >> 16));
  } else {
    acc[0] = acc[1] = acc[2] = acc[3] = 0.0f;
  }
  int e1 = offs[v + 1];
  int e = offs[v] + s;
  for (; e + 8 < e1; e += 16) {
    int u0 = csrc[e], u1 = csrc[e + 8];
    uint2 q0 = Z2[(size_t)u0 * 8 + fl];
    uint2 q1 = Z2[(size_t)u1 * 8 + fl];
    acc[0] += b2f((ushort)(q0.x & 0xFFFF)) + b2f((ushort)(q1.x & 0xFFFF));
    acc[1] += b2f((ushort)(q0.x >> 16))    + b2f((ushort)(q1.x >> 16));
    acc[2] += b2f((ushort)(q0.y & 0xFFFF)) + b2f((ushort)(q1.y & 0xFFFF));
    acc[3] += b2f((ushort)(q0.y >> 16))    + b2f((ushort)(q1.y >> 16));
  }
  for (; e < e1; e += 8) {
    uint2 qq = Z2[(size_t)csrc[e] * 8 + fl];
    acc[0] += b2f((ushort)(qq.x & 0xFFFF)); acc[1] += b2f((ushort)(qq.x >> 16));
    acc[2] += b2f((ushort)(qq.y & 0xFFFF)); acc[3] += b2f((ushort)(qq.y >> 16));
  }
#pragma unroll
  for (int j = 0; j < 4; ++j) {
    acc[j] += __shfl_xor(acc[j], 8);
    acc[j] += __shfl_xor(acc[j], 16);
    acc[j] += __shfl_xor(acc[j], 32);
  }
  if (s == 0 && fl < 5) {
    float4 w;
    w.x = acc[0] * dv + b3[fl * 4 + 0];
    w.y = acc[1] * dv + b3[fl * 4 + 1];
    w.z = acc[2] * dv + b3[fl * 4 + 2];
    w.w = acc[3] * dv + b3[fl * 4 + 3];
    *reinterpret_cast<float4*>(out + (size_t)v * 20 + fl * 4) = w;
  }
}

// ---------------- Fused-column GEMM: 512 threads, BM=128 x BN=256, A read once ----------------
template<int KT, bool EPI, bool SCALE>
__global__ __launch_bounds__(512) void k_gemmW(const ushort* __restrict__ A,
                                               const ushort* __restrict__ Bt,   // [256 cols][KT]
                                               ushort* __restrict__ Out,
                                               const float* __restrict__ bnA,
                                               const float* __restrict__ bnB,
                                               const float* __restrict__ dinv) {
  constexpr int BK = 64;
  constexpr int NT = KT / BK;
  __shared__ ushort Alds[128 * 64];
  __shared__ ushort Blds[256 * 64];
  int tid = threadIdx.x;
  int lane = tid & 63;
  int wave = tid >> 6;            // 0..7
  int wm = wave >> 2, wn = wave & 3;
  size_t row0 = (size_t)blockIdx.x * 128;
  int laneLo = lane & 15, laneHi = lane >> 4;

  f32x4 acc[4][4];
#pragma unroll
  for (int i = 0; i < 4; ++i)
#pragma unroll
    for (int j = 0; j < 4; ++j)
#pragma unroll
      for (int r = 0; r < 4; ++r) acc[i][j][r] = 0.0f;

  for (int t = 0; t < NT; ++t) {
    int k0 = t * BK;
#pragma unroll
    for (int is = 0; is < 2; ++is) {           // A: 128 rows x 8 slots = 1024
      int idx = is * 512 + tid;
      int r = idx >> 3, c = idx & 7;
      size_t gr = row0 + r; if (gr >= NN) gr = NN - 1;
      gload16(A + gr * KT + k0 + c * 8, &Alds[(idx & ~63) * 8]);
    }
#pragma unroll
    for (int is = 0; is < 4; ++is) {           // B: 256 rows x 8 slots = 2048
      int idx = is * 512 + tid;
      int r = idx >> 3, c = idx & 7;
      gload16(Bt + (size_t)r * KT + k0 + c * 8, &Blds[(idx & ~63) * 8]);
    }
    __syncthreads();
#pragma unroll
    for (int kk = 0; kk < BK; kk += 32) {
      short8 af[4]; short8 bf[4];
#pragma unroll
      for (int fm = 0; fm < 4; ++fm)
        af[fm] = *reinterpret_cast<const short8*>(&Alds[(wm * 64 + fm * 16 + laneLo) * 64 + kk + laneHi * 8]);
#pragma unroll
      for (int fn = 0; fn < 4; ++fn)
        bf[fn] = *reinterpret_cast<const short8*>(&Blds[(wn * 64 + fn * 16 + laneLo) * 64 + kk + laneHi * 8]);
#pragma unroll
      for (int fm = 0; fm < 4; ++fm)
#pragma unroll
        for (int fn = 0; fn < 4; ++fn)
          acc[fm][fn] = __builtin_amdgcn_mfma_f32_16x16x32_bf16(af[fm], bf[fn], acc[fm][fn], 0, 0, 0);
    }
    __syncthreads();
  }

  int lr = laneHi * 4, lc = laneLo;
#pragma unroll
  for (int fm = 0; fm < 4; ++fm) {
#pragma unroll
    for (int r = 0; r < 4; ++r) {
      size_t grow = row0 + wm * 64 + fm * 16 + lr + r;
      if (grow >= NN) continue;
      float ds = 1.0f;
      if constexpr (SCALE) ds = dinv[grow];
#pragma unroll
      for (int fn = 0; fn < 4; ++fn) {
        int gcol = wn * 64 + fn * 16 + lc;
        float v = acc[fm][fn][r];
        if constexpr (EPI) v = fmaxf(v * bnA[gcol] + bnB[gcol], 0.0f);
        if constexpr (SCALE) v *= ds;
        Out[grow * 256 + gcol] = f2bf(v);
      }
    }
  }
}

// ---------------- narrow GEMM for G3 (256->32), R6 structure ----------------
template<int KTOT, int BN, bool EPI, bool SCALE>
__global__ __launch_bounds__(256) void k_gemm(const ushort* __restrict__ A,
                                              const ushort* __restrict__ Bt,
                                              ushort* __restrict__ Out,
                                              const float* __restrict__ bnA,
                                              const float* __restrict__ bnB,
                                              const float* __restrict__ dinv, int outW) {
  constexpr int BM = 128, BK = 64;
  constexpr int WN = (BN == 128) ? 64 : 16;
  constexpr int WM = 64;
  constexpr int FM = WM / 16, FN = WN / 16;
  __shared__ ushort Alds[BM * BK];
  __shared__ ushort Blds[BN * BK];
  int tid = threadIdx.x;
  int lane = tid & 63;
  int wave = tid >> 6;
  int wm = wave >> 1, wn = wave & 1;
  size_t row0 = (size_t)blockIdx.x * BM;
  int col0 = blockIdx.y * BN;

  f32x4 acc[FM][FN];
#pragma unroll
  for (int i = 0; i < FM; ++i)
#pragma unroll
    for (int j = 0; j < FN; ++j)
#pragma unroll
      for (int r = 0; r < 4; ++r) acc[i][j][r] = 0.0f;

  for (int k0 = 0; k0 < KTOT; k0 += BK) {
#pragma unroll
    for (int is = 0; is < 4; ++is) {
      int idx = is * 256 + tid;
      int r = idx >> 3, c = idx & 7;
      size_t gr = row0 + r; if (gr >= NN) gr = NN - 1;
      gload16(A + gr * KTOT + k0 + c * 8, &Alds[(size_t)(idx & ~63) * 8]);
    }
#pragma unroll
    for (int is = 0; is < BN / 32; ++is) {
      int idx = is * 256 + tid;
      int r = idx >> 3, c = idx & 7;
      gload16(Bt + (size_t)(col0 + r) * KTOT + k0 + c * 8, &Blds[(size_t)(idx & ~63) * 8]);
    }
    __syncthreads();
#pragma unroll
    for (int kk = 0; kk < BK; kk += 32) {
      short8 af[FM]; short8 bfr[FN];
#pragma unroll
      for (int fm = 0; fm < FM; ++fm)
        af[fm] = *reinterpret_cast<const short8*>(&Alds[(wm * WM + fm * 16 + (lane & 15)) * BK + kk + (lane >> 4) * 8]);
#pragma unroll
      for (int fn = 0; fn < FN; ++fn)
        bfr[fn] = *reinterpret_cast<const short8*>(&Blds[(wn * WN + fn * 16 + (lane & 15)) * BK + kk + (lane >> 4) * 8]);
#pragma unroll
      for (int fm = 0; fm < FM; ++fm)
#pragma unroll
        for (int fn = 0; fn < FN; ++fn)
          acc[fm][fn] = __builtin_amdgcn_mfma_f32_16x16x32_bf16(af[fm], bfr[fn], acc[fm][fn], 0, 0, 0);
    }
    __syncthreads();
  }

  int lr = (lane >> 4) * 4, lc = lane & 15;
#pragma unroll
  for (int fm = 0; fm < FM; ++fm) {
#pragma unroll
    for (int r = 0; r < 4; ++r) {
      size_t grow = row0 + wm * WM + fm * 16 + lr + r;
      if (grow >= NN) continue;
      float ds = 1.0f;
      if constexpr (SCALE) ds = dinv[grow];
#pragma unroll
      for (int fn = 0; fn < FN; ++fn) {
        int gcol = col0 + wn * WN + fn * 16 + lc;
        float v = acc[fm][fn][r];
        if constexpr (EPI) v = fmaxf(v * bnA[gcol] + bnB[gcol], 0.0f);
        if constexpr (SCALE) v *= ds;
        Out[grow * outW + gcol] = f2bf(v);
      }
    }
  }
}

extern "C" void kernel_launch(void* const* d_in, const int* in_sizes, int n_in,
                              void* d_out, int out_size, void* d_ws, size_t ws_size,
                              hipStream_t stream) {
  (void)in_sizes; (void)n_in; (void)out_size; (void)ws_size;
  const float* x     = (const float*)d_in[0];
  const int*   ei    = (const int*)d_in[1];
  const float* W0    = (const float*)d_in[2];
  const float* b0    = (const float*)d_in[3];
  const float* W1    = (const float*)d_in[4];
  const float* b1    = (const float*)d_in[5];
  const float* W2    = (const float*)d_in[6];
  const float* b2    = (const float*)d_in[7];
  const float* W3    = (const float*)d_in[8];
  const float* b3    = (const float*)d_in[9];
  const float* gamma = (const float*)d_in[10];
  const float* beta  = (const float*)d_in[11];
  const float* rm    = (const float*)d_in[12];
  const float* rv    = (const float*)d_in[13];
  const int* src = ei;
  const int* dst = ei + NE;
  float* out = (float*)d_out;

  char* ws = (char*)d_ws;
  size_t off = 0;
  auto alloc = [&](size_t bytes) -> void* {
    void* p = ws + off; off += (bytes + 255) & ~(size_t)255; return p;
  };
  int*    ghist = (int*)alloc((size_t)NBKT * NBA * 4);
  int*    gbase = (int*)alloc((size_t)NBKT * NBA * 4);
  int*    btot  = (int*)alloc(NBKT * 4);
  int*    bbase = (int*)alloc(NBKT * 4);
  uint*   bpack = (uint*)alloc((size_t)NE * 4);
  int*    offs  = (int*)alloc((NN + 1) * (size_t)4);
  int*    csrc  = (int*)alloc((size_t)NE * 4);
  float*  dinv  = (float*)alloc(NN * 4);
  ushort* W0t   = (ushort*)alloc(256 * 128 * 2);
  ushort* W1t   = (ushort*)alloc(256 * 256 * 2);
  ushort* W2t   = (ushort*)alloc(256 * 256 * 2);
  ushort* W3t   = (ushort*)alloc(32 * 256 * 2);
  float*  bnA   = (float*)alloc(3 * 256 * 4);
  float*  bnB   = (float*)alloc(3 * 256 * 4);
  ushort* bufS  = (ushort*)alloc((size_t)NN * 128 * 2);   // x_bf16*dinv / z3*dinv
  ushort* bufA  = (ushort*)alloc((size_t)NN * 256 * 2);   // agg outputs
  ushort* bufB  = (ushort*)alloc((size_t)NN * 256 * 2);   // gemm outputs

  k_hist<<<NBA, 256, 0, stream>>>(dst, ghist);
  k_gscanA<<<NBKT, NBA, 0, stream>>>(ghist, gbase, btot);
  k_bscan<<<1, 512, 0, stream>>>(btot, bbase, offs);
  k_scatter<<<NBA, 256, 0, stream>>>(src, dst, bbase, gbase, bpack);
  k_bucketB<<<NBKT, 256, 0, stream>>>(bpack, btot, bbase, csrc, offs, dinv);
  k_prep<<<256, 256, 0, stream>>>(W0, W1, W2, W3, b0, b1, b2, gamma, beta, rm, rv,
                                  W0t, W1t, W2t, W3t, bnA, bnB);
  k_convx<<<2048, 256, 0, stream>>>((const float4*)x, (uint2*)bufS, dinv);

  const int aggBlocks = (NN + 3) / 4;   // 25000
  const int gemmBlocks = (NN + 127) / 128;   // 782
  dim3 gLast(gemmBlocks, 1);

  // L0: aggregate(x*dinv)[128] -> GEMM 128->256 (+BN+ReLU, out *= dinv)
  k_agg128<<<aggBlocks, 256, 0, stream>>>(bufS, offs, csrc, dinv, bufA);
  k_gemmW<128, true, true><<<gemmBlocks, 512, 0, stream>>>(bufA, W0t, bufB, bnA, bnB, dinv);
  // L1 (out *= dinv, feeds agg2)
  k_agg256<<<aggBlocks, 256, 0, stream>>>(bufB, offs, csrc, dinv, bufA);
  k_gemmW<256, true, true><<<gemmBlocks, 512, 0, stream>>>(bufA, W1t, bufB, bnA + 256, bnB + 256, dinv);
  // L2 (NO dinv scale — output feeds GEMM3 directly)
  k_agg256<<<aggBlocks, 256, 0, stream>>>(bufB, offs, csrc, dinv, bufA);
  k_gemmW<256, true, false><<<gemmBlocks, 512, 0, stream>>>(bufA, W2t, bufB, bnA + 512, bnB + 512, nullptr);
  // L3: GEMM 256->20 (padded 32, out *= dinv), then aggregate + b3 -> fp32 out
  k_gemm<256, 32, false, true><<<gLast, 256, 0, stream>>>(bufB, W3t, bufS, nullptr, nullptr, dinv, 32);
  k_aggfin<<<aggBlocks, 256, 0, stream>>>(bufS, offs, csrc, dinv, b3, out);
}

// Round 11
// 522.777 us; speedup vs baseline: 1.8986x; 1.0552x over previous
//
#include <hip/hip_runtime.h>
#include <hip/hip_bf16.h>
#include <stdint.h>

#define NN 100000
#define NE 1600000
#define BNEPS 1e-5f
#define NBKT 391            // ceil(NN/256)
#define NBA  512            // phase-A blocks
#define CHUNK ((NE + NBA - 1) / NBA)   // 3125

using short8 = __attribute__((ext_vector_type(8))) short;
using f32x4  = __attribute__((ext_vector_type(4))) float;

__device__ __forceinline__ float b2f(ushort u) {
  union { uint32_t u; float f; } c; c.u = ((uint32_t)u) << 16; return c.f;
}
__device__ __forceinline__ ushort f2bf(float f) {
  union { float f; uint32_t u; } c; c.f = f;
  uint32_t r = (c.u + 0x7FFFu + ((c.u >> 16) & 1u)) >> 16;
  return (ushort)r;
}
__device__ __forceinline__ uint pk(float a, float b) {
  return (uint)f2bf(a) | ((uint)f2bf(b) << 16);
}
__device__ __forceinline__ void gload16(const void* g, void* lds) {
  __builtin_amdgcn_global_load_lds((const __attribute__((address_space(1))) void*)g,
                                   (__attribute__((address_space(3))) void*)lds,
                                   16, 0, 0);
}
__device__ __forceinline__ void add16(float* a, uint4 q) {
  a[0] += b2f((ushort)(q.x & 0xFFFF)); a[1] += b2f((ushort)(q.x >> 16));
  a[2] += b2f((ushort)(q.y & 0xFFFF)); a[3] += b2f((ushort)(q.y >> 16));
  a[4] += b2f((ushort)(q.z & 0xFFFF)); a[5] += b2f((ushort)(q.z >> 16));
  a[6] += b2f((ushort)(q.w & 0xFFFF)); a[7] += b2f((ushort)(q.w >> 16));
}
__device__ __forceinline__ void set16(float* a, uint4 q) {
  a[0] = b2f((ushort)(q.x & 0xFFFF)); a[1] = b2f((ushort)(q.x >> 16));
  a[2] = b2f((ushort)(q.y & 0xFFFF)); a[3] = b2f((ushort)(q.y >> 16));
  a[4] = b2f((ushort)(q.z & 0xFFFF)); a[5] = b2f((ushort)(q.z >> 16));
  a[6] = b2f((ushort)(q.w & 0xFFFF)); a[7] = b2f((ushort)(q.w >> 16));
}

// ---------------- CSR build: LDS-histogram counting sort ----------------
__global__ __launch_bounds__(256) void k_hist(const int* __restrict__ dst, int* __restrict__ ghist) {
  __shared__ int h[NBKT];
  for (int t = threadIdx.x; t < NBKT; t += 256) h[t] = 0;
  __syncthreads();
  int e0 = blockIdx.x * CHUNK;
  int e1 = e0 + CHUNK; if (e1 > NE) e1 = NE;
  for (int e = e0 + threadIdx.x; e < e1; e += 256)
    atomicAdd(&h[((uint)dst[e]) >> 8], 1);
  __syncthreads();
  for (int t = threadIdx.x; t < NBKT; t += 256) ghist[t * NBA + blockIdx.x] = h[t];
}

__global__ __launch_bounds__(512) void k_gscanA(const int* __restrict__ ghist, int* __restrict__ gbase,
                                                int* __restrict__ btot) {
  __shared__ int s[NBA];
  int t = threadIdx.x, b = blockIdx.x;
  int d = ghist[b * NBA + t];
  s[t] = d; __syncthreads();
  int val = d;
  for (int sh = 1; sh < NBA; sh <<= 1) {
    int tv = (t >= sh) ? s[t - sh] : 0;
    __syncthreads();
    val += tv; s[t] = val;
    __syncthreads();
  }
  gbase[b * NBA + t] = val - d;
  if (t == NBA - 1) btot[b] = val;
}

__global__ __launch_bounds__(512) void k_bscan(const int* __restrict__ btot, int* __restrict__ bbase,
                                               int* __restrict__ offs) {
  __shared__ int s[512];
  int t = threadIdx.x;
  int d = (t < NBKT) ? btot[t] : 0;
  s[t] = d; __syncthreads();
  int val = d;
  for (int sh = 1; sh < 512; sh <<= 1) {
    int tv = (t >= sh) ? s[t - sh] : 0;
    __syncthreads();
    val += tv; s[t] = val;
    __syncthreads();
  }
  if (t < NBKT) bbase[t] = val - d;
  if (t == 0) offs[NN] = NE;
}

__global__ __launch_bounds__(256) void k_scatter(const int* __restrict__ src, const int* __restrict__ dst,
                                                 const int* __restrict__ bbase, const int* __restrict__ gbase,
                                                 uint* __restrict__ bpack) {
  __shared__ int lbase[NBKT];
  for (int t = threadIdx.x; t < NBKT; t += 256)
    lbase[t] = bbase[t] + gbase[t * NBA + blockIdx.x];
  __syncthreads();
  int e0 = blockIdx.x * CHUNK;
  int e1 = e0 + CHUNK; if (e1 > NE) e1 = NE;
  for (int e = e0 + threadIdx.x; e < e1; e += 256) {
    int d = dst[e];
    int pos = atomicAdd(&lbase[((uint)d) >> 8], 1);
    bpack[pos] = ((uint)(d & 255) << 17) | (uint)src[e];
  }
}

__global__ __launch_bounds__(256) void k_bucketB(const uint* __restrict__ bpack, const int* __restrict__ btot,
                                                 const int* __restrict__ bbase, int* __restrict__ csrc,
                                                 int* __restrict__ offs, float* __restrict__ dinv) {
  __shared__ int hist[256];
  __shared__ int sc[256];
  __shared__ int loc[256];
  int b = blockIdx.x, t = threadIdx.x;
  int cnt = btot[b], base = bbase[b];
  const uint* bp = bpack + base;
  hist[t] = 0; __syncthreads();
  for (int i = t; i < cnt; i += 256) atomicAdd(&hist[bp[i] >> 17], 1);
  __syncthreads();
  int d = hist[t];
  sc[t] = d; __syncthreads();
  int val = d;
  for (int sh = 1; sh < 256; sh <<= 1) {
    int tv = (t >= sh) ? sc[t - sh] : 0;
    __syncthreads();
    val += tv; sc[t] = val;
    __syncthreads();
  }
  loc[t] = val - d;
  int n = b * 256 + t;
  if (n < NN) {
    offs[n] = base + val - d;
    dinv[n] = rsqrtf((float)d + 1.0f);
  }
  __syncthreads();
  for (int i = t; i < cnt; i += 256) {
    uint p = bp[i];
    int l = p >> 17, s = p & 0x1FFFF;
    int pos = atomicAdd(&loc[l], 1);
    csrc[base + pos] = s;
  }
}

// ---------------- weight prep ----------------
__global__ __launch_bounds__(256) void k_prep(
    const float* __restrict__ W0, const float* __restrict__ W1, const float* __restrict__ W2,
    const float* __restrict__ W3, const float* __restrict__ b0, const float* __restrict__ b1,
    const float* __restrict__ b2, const float* __restrict__ gamma, const float* __restrict__ beta,
    const float* __restrict__ rm, const float* __restrict__ rv,
    ushort* __restrict__ W0t, ushort* __restrict__ W1t, ushort* __restrict__ W2t,
    ushort* __restrict__ W3t, float* __restrict__ bnA, float* __restrict__ bnB) {
  int tid = blockIdx.x * blockDim.x + threadIdx.x;
  int nthr = gridDim.x * blockDim.x;
  for (int i = tid; i < 256 * 128; i += nthr) { int m = i >> 7, k = i & 127; W0t[i] = f2bf(W0[k * 256 + m]); }
  for (int i = tid; i < 256 * 256; i += nthr) {
    int m = i >> 8, k = i & 255;
    W1t[i] = f2bf(W1[k * 256 + m]);
    W2t[i] = f2bf(W2[k * 256 + m]);
  }
  for (int i = tid; i < 32 * 256; i += nthr) {
    int m = i >> 8, k = i & 255;
    W3t[i] = (m < 20) ? f2bf(W3[k * 20 + m]) : (ushort)0;
  }
  for (int i = tid; i < 3 * 256; i += nthr) {
    int l = i >> 8, c = i & 255;
    float A = gamma[i] * rsqrtf(rv[i] + BNEPS);
    float bb = (l == 0) ? b0[c] : (l == 1) ? b1[c] : b2[c];
    bnA[i] = A;
    bnB[i] = (bb - rm[i]) * A + beta[i];
  }
}

// ---------------- x -> bf16, pre-scaled by dinv[row] ----------------
__global__ __launch_bounds__(256) void k_convx(const float4* __restrict__ x, uint2* __restrict__ xb,
                                               const float* __restrict__ dinv) {
  int stride = gridDim.x * blockDim.x;
  const int n4 = NN * 128 / 4;
  for (int i = blockIdx.x * blockDim.x + threadIdx.x; i < n4; i += stride) {
    float4 f = x[i];
    float dv = dinv[i >> 5];
    uint2 o;
    o.x = pk(f.x * dv, f.y * dv);
    o.y = pk(f.z * dv, f.w * dv);
    xb[i] = o;
  }
}

// ---------------- gather aggregation (R6 config — structural floor) ----------------
// Z rows PRE-SCALED by dinv[u]:  out[v] = (zs[v] + sum_u zs[u]) * dinv[v]

__global__ __launch_bounds__(256) void k_agg256(const ushort* __restrict__ Z,
                                                const int* __restrict__ offs, const int* __restrict__ csrc,
                                                const float* __restrict__ dinv, ushort* __restrict__ Outb) {
  int wave = threadIdx.x >> 6, lane = threadIdx.x & 63;
  int v = blockIdx.x * 4 + wave;
  if (v >= NN) return;
  float dv = dinv[v];
  int p = lane >> 5, fl = lane & 31;
  const uint4* Z4 = reinterpret_cast<const uint4*>(Z);   // 32 uint4 per row
  float acc[8];
  if (p == 0) {
    set16(acc, Z4[(size_t)v * 32 + fl]);
  } else {
#pragma unroll
    for (int j = 0; j < 8; ++j) acc[j] = 0.0f;
  }
  int e1 = offs[v + 1];
  int e = offs[v] + p;
  for (; e + 6 < e1; e += 8) {
    int u0 = csrc[e], u1 = csrc[e + 2], u2 = csrc[e + 4], u3 = csrc[e + 6];
    uint4 q0 = Z4[(size_t)u0 * 32 + fl];
    uint4 q1 = Z4[(size_t)u1 * 32 + fl];
    uint4 q2 = Z4[(size_t)u2 * 32 + fl];
    uint4 q3 = Z4[(size_t)u3 * 32 + fl];
    add16(acc, q0); add16(acc, q1); add16(acc, q2); add16(acc, q3);
  }
  for (; e < e1; e += 2) add16(acc, Z4[(size_t)csrc[e] * 32 + fl]);
#pragma unroll
  for (int j = 0; j < 8; ++j) acc[j] += __shfl_xor(acc[j], 32);
  int o = p * 4;
  uint2 w;
  w.x = pk(acc[o + 0] * dv, acc[o + 1] * dv);
  w.y = pk(acc[o + 2] * dv, acc[o + 3] * dv);
  reinterpret_cast<uint2*>(Outb)[(size_t)v * 64 + fl * 2 + p] = w;
}

__global__ __launch_bounds__(256) void k_agg128(const ushort* __restrict__ Z,
                                                const int* __restrict__ offs, const int* __restrict__ csrc,
                                                const float* __restrict__ dinv, ushort* __restrict__ Outb) {
  int wave = threadIdx.x >> 6, lane = threadIdx.x & 63;
  int v = blockIdx.x * 4 + wave;
  if (v >= NN) return;
  float dv = dinv[v];
  int q = lane >> 4, fl = lane & 15;
  const uint4* Z4 = reinterpret_cast<const uint4*>(Z);   // 16 uint4 per row
  float acc[8];
  if (q == 0) {
    set16(acc, Z4[(size_t)v * 16 + fl]);
  } else {
#pragma unroll
    for (int j = 0; j < 8; ++j) acc[j] = 0.0f;
  }
  int e1 = offs[v + 1];
  int e = offs[v] + q;
  for (; e + 12 < e1; e += 16) {
    int u0 = csrc[e], u1 = csrc[e + 4], u2 = csrc[e + 8], u3 = csrc[e + 12];
    uint4 q0 = Z4[(size_t)u0 * 16 + fl];
    uint4 q1 = Z4[(size_t)u1 * 16 + fl];
    uint4 q2 = Z4[(size_t)u2 * 16 + fl];
    uint4 q3 = Z4[(size_t)u3 * 16 + fl];
    add16(acc, q0); add16(acc, q1); add16(acc, q2); add16(acc, q3);
  }
  for (; e < e1; e += 4) add16(acc, Z4[(size_t)csrc[e] * 16 + fl]);
#pragma unroll
  for (int j = 0; j < 8; ++j) {
    acc[j] += __shfl_xor(acc[j], 16);
    acc[j] += __shfl_xor(acc[j], 32);
  }
  uint w = pk(acc[2 * q] * dv, acc[2 * q + 1] * dv);
  reinterpret_cast<uint*>(Outb)[(size_t)v * 64 + fl * 4 + q] = w;
}

__global__ __launch_bounds__(256) void k_aggfin(const ushort* __restrict__ Z,
                                                const int* __restrict__ offs, const int* __restrict__ csrc,
                                                const float* __restrict__ dinv, const float* __restrict__ b3,
                                                float* __restrict__ out) {
  int wave = threadIdx.x >> 6, lane = threadIdx.x & 63;
  int v = blockIdx.x * 4 + wave;
  if (v >= NN) return;
  float dv = dinv[v];
  int s = lane >> 3, fl = lane & 7;
  const uint2* Z2 = reinterpret_cast<const uint2*>(Z);   // 8 uint2 per row
  float acc[4];
  if (s == 0) {
    uint2 qq = Z2[(size_t)v * 8 + fl];
    acc[0] = b2f((ushort)(qq.x & 0xFFFF)); acc[1] = b2f((ushort)(qq.x >> 16));
    acc[2] = b2f((ushort)(qq.y & 0xFFFF)); acc[3] = b2f((ushort)(qq.y >> 16));
  } else {
    acc[0] = acc[1] = acc[2] = acc[3] = 0.0f;
  }
  int e1 = offs[v + 1];
  int e = offs[v] + s;
  for (; e + 8 < e1; e += 16) {
    int u0 = csrc[e], u1 = csrc[e + 8];
    uint2 q0 = Z2[(size_t)u0 * 8 + fl];
    uint2 q1 = Z2[(size_t)u1 * 8 + fl];
    acc[0] += b2f((ushort)(q0.x & 0xFFFF)) + b2f((ushort)(q1.x & 0xFFFF));
    acc[1] += b2f((ushort)(q0.x >> 16))    + b2f((ushort)(q1.x >> 16));
    acc[2] += b2f((ushort)(q0.y & 0xFFFF)) + b2f((ushort)(q1.y & 0xFFFF));
    acc[3] += b2f((ushort)(q0.y >> 16))    + b2f((ushort)(q1.y >> 16));
  }
  for (; e < e1; e += 8) {
    uint2 qq = Z2[(size_t)csrc[e] * 8 + fl];
    acc[0] += b2f((ushort)(qq.x & 0xFFFF)); acc[1] += b2f((ushort)(qq.x >> 16));
    acc[2] += b2f((ushort)(qq.y & 0xFFFF)); acc[3] += b2f((ushort)(qq.y >> 16));
  }
#pragma unroll
  for (int j = 0; j < 4; ++j) {
    acc[j] += __shfl_xor(acc[j], 8);
    acc[j] += __shfl_xor(acc[j], 16);
    acc[j] += __shfl_xor(acc[j], 32);
  }
  if (s == 0 && fl < 5) {
    float4 w;
    w.x = acc[0] * dv + b3[fl * 4 + 0];
    w.y = acc[1] * dv + b3[fl * 4 + 1];
    w.z = acc[2] * dv + b3[fl * 4 + 2];
    w.w = acc[3] * dv + b3[fl * 4 + 3];
    *reinterpret_cast<float4*>(out + (size_t)v * 20 + fl * 4) = w;
  }
}

// ---------------- MFMA GEMM (R6 structure — best measured) ----------------
template<int KTOT, int BN, bool EPI, bool SCALE>
__global__ __launch_bounds__(256) void k_gemm(const ushort* __restrict__ A,
                                              const ushort* __restrict__ Bt,   // [cols][KTOT]
                                              ushort* __restrict__ Out,
                                              const float* __restrict__ bnA,
                                              const float* __restrict__ bnB,
                                              const float* __restrict__ dinv, int outW) {
  constexpr int BM = 128, BK = 64;
  constexpr int WN = (BN == 128) ? 64 : 16;
  constexpr int WM = 64;
  constexpr int FM = WM / 16, FN = WN / 16;
  __shared__ ushort Alds[BM * BK];
  __shared__ ushort Blds[BN * BK];
  int tid = threadIdx.x;
  int lane = tid & 63;
  int wave = tid >> 6;
  int wm = wave >> 1, wn = wave & 1;
  size_t row0 = (size_t)blockIdx.x * BM;
  int col0 = blockIdx.y * BN;

  f32x4 acc[FM][FN];
#pragma unroll
  for (int i = 0; i < FM; ++i)
#pragma unroll
    for (int j = 0; j < FN; ++j)
#pragma unroll
      for (int r = 0; r < 4; ++r) acc[i][j][r] = 0.0f;

  for (int k0 = 0; k0 < KTOT; k0 += BK) {
#pragma unroll
    for (int is = 0; is < 4; ++is) {
      int idx = is * 256 + tid;
      int r = idx >> 3, c = idx & 7;
      size_t gr = row0 + r; if (gr >= NN) gr = NN - 1;
      gload16(A + gr * KTOT + k0 + c * 8, &Alds[(size_t)(idx & ~63) * 8]);
    }
#pragma unroll
    for (int is = 0; is < BN / 32; ++is) {
      int idx = is * 256 + tid;
      int r = idx >> 3, c = idx & 7;
      gload16(Bt + (size_t)(col0 + r) * KTOT + k0 + c * 8, &Blds[(size_t)(idx & ~63) * 8]);
    }
    __syncthreads();
#pragma unroll
    for (int kk = 0; kk < BK; kk += 32) {
      short8 af[FM]; short8 bfr[FN];
#pragma unroll
      for (int fm = 0; fm < FM; ++fm)
        af[fm] = *reinterpret_cast<const short8*>(&Alds[(wm * WM + fm * 16 + (lane & 15)) * BK + kk + (lane >> 4) * 8]);
#pragma unroll
      for (int fn = 0; fn < FN; ++fn)
        bfr[fn] = *reinterpret_cast<const short8*>(&Blds[(wn * WN + fn * 16 + (lane & 15)) * BK + kk + (lane >> 4) * 8]);
#pragma unroll
      for (int fm = 0; fm < FM; ++fm)
#pragma unroll
        for (int fn = 0; fn < FN; ++fn)
          acc[fm][fn] = __builtin_amdgcn_mfma_f32_16x16x32_bf16(af[fm], bfr[fn], acc[fm][fn], 0, 0, 0);
    }
    __syncthreads();
  }

  int lr = (lane >> 4) * 4, lc = lane & 15;
#pragma unroll
  for (int fm = 0; fm < FM; ++fm) {
#pragma unroll
    for (int r = 0; r < 4; ++r) {
      size_t grow = row0 + wm * WM + fm * 16 + lr + r;
      if (grow >= NN) continue;
      float ds = 1.0f;
      if constexpr (SCALE) ds = dinv[grow];
#pragma unroll
      for (int fn = 0; fn < FN; ++fn) {
        int gcol = col0 + wn * WN + fn * 16 + lc;
        float v = acc[fm][fn][r];
        if constexpr (EPI) v = fmaxf(v * bnA[gcol] + bnB[gcol], 0.0f);
        if constexpr (SCALE) v *= ds;
        Out[grow * outW + gcol] = f2bf(v);
      }
    }
  }
}

extern "C" void kernel_launch(void* const* d_in, const int* in_sizes, int n_in,
                              void* d_out, int out_size, void* d_ws, size_t ws_size,
                              hipStream_t stream) {
  (void)in_sizes; (void)n_in; (void)out_size; (void)ws_size;
  const float* x     = (const float*)d_in[0];
  const int*   ei    = (const int*)d_in[1];
  const float* W0    = (const float*)d_in[2];
  const float* b0    = (const float*)d_in[3];
  const float* W1    = (const float*)d_in[4];
  const float* b1    = (const float*)d_in[5];
  const float* W2    = (const float*)d_in[6];
  const float* b2    = (const float*)d_in[7];
  const float* W3    = (const float*)d_in[8];
  const float* b3    = (const float*)d_in[9];
  const float* gamma = (const float*)d_in[10];
  const float* beta  = (const float*)d_in[11];
  const float* rm    = (const float*)d_in[12];
  const float* rv    = (const float*)d_in[13];
  const int* src = ei;
  const int* dst = ei + NE;
  float* out = (float*)d_out;

  char* ws = (char*)d_ws;
  size_t off = 0;
  auto alloc = [&](size_t bytes) -> void* {
    void* p = ws + off; off += (bytes + 255) & ~(size_t)255; return p;
  };
  int*    ghist = (int*)alloc((size_t)NBKT * NBA * 4);
  int*    gbase = (int*)alloc((size_t)NBKT * NBA * 4);
  int*    btot  = (int*)alloc(NBKT * 4);
  int*    bbase = (int*)alloc(NBKT * 4);
  uint*   bpack = (uint*)alloc((size_t)NE * 4);
  int*    offs  = (int*)alloc((NN + 1) * (size_t)4);
  int*    csrc  = (int*)alloc((size_t)NE * 4);
  float*  dinv  = (float*)alloc(NN * 4);
  ushort* W0t   = (ushort*)alloc(256 * 128 * 2);
  ushort* W1t   = (ushort*)alloc(256 * 256 * 2);
  ushort* W2t   = (ushort*)alloc(256 * 256 * 2);
  ushort* W3t   = (ushort*)alloc(32 * 256 * 2);
  float*  bnA   = (float*)alloc(3 * 256 * 4);
  float*  bnB   = (float*)alloc(3 * 256 * 4);
  ushort* bufS  = (ushort*)alloc((size_t)NN * 128 * 2);   // x_bf16*dinv / z3*dinv
  ushort* bufA  = (ushort*)alloc((size_t)NN * 256 * 2);   // agg outputs
  ushort* bufB  = (ushort*)alloc((size_t)NN * 256 * 2);   // gemm outputs

  k_hist<<<NBA, 256, 0, stream>>>(dst, ghist);
  k_gscanA<<<NBKT, NBA, 0, stream>>>(ghist, gbase, btot);
  k_bscan<<<1, 512, 0, stream>>>(btot, bbase, offs);
  k_scatter<<<NBA, 256, 0, stream>>>(src, dst, bbase, gbase, bpack);
  k_bucketB<<<NBKT, 256, 0, stream>>>(bpack, btot, bbase, csrc, offs, dinv);
  k_prep<<<256, 256, 0, stream>>>(W0, W1, W2, W3, b0, b1, b2, gamma, beta, rm, rv,
                                  W0t, W1t, W2t, W3t, bnA, bnB);
  k_convx<<<2048, 256, 0, stream>>>((const float4*)x, (uint2*)bufS, dinv);

  const int aggBlocks = (NN + 3) / 4;   // 25000
  dim3 gMain((NN + 127) / 128, 2);
  dim3 gLast((NN + 127) / 128, 1);

  // L0: aggregate(x*dinv)[128] -> GEMM 128->256 (+BN+ReLU, out *= dinv)
  k_agg128<<<aggBlocks, 256, 0, stream>>>(bufS, offs, csrc, dinv, bufA);
  k_gemm<128, 128, true, true><<<gMain, 256, 0, stream>>>(bufA, W0t, bufB, bnA, bnB, dinv, 256);
  // L1 (out *= dinv, feeds agg2)
  k_agg256<<<aggBlocks, 256, 0, stream>>>(bufB, offs, csrc, dinv, bufA);
  k_gemm<256, 128, true, true><<<gMain, 256, 0, stream>>>(bufA, W1t, bufB, bnA + 256, bnB + 256, dinv, 256);
  // L2 (NO dinv scale — output feeds GEMM3 directly)
  k_agg256<<<aggBlocks, 256, 0, stream>>>(bufB, offs, csrc, dinv, bufA);
  k_gemm<256, 128, true, false><<<gMain, 256, 0, stream>>>(bufA, W2t, bufB, bnA + 512, bnB + 512, nullptr, 256);
  // L3: GEMM 256->20 (padded 32, out *= dinv), then aggregate + b3 -> fp32 out
  k_gemm<256, 32, false, true><<<gLast, 256, 0, stream>>>(bufB, W3t, bufS, nullptr, nullptr, dinv, 32);
  k_aggfin<<<aggBlocks, 256, 0, stream>>>(bufS, offs, csrc, dinv, b3, out);
}